// Round 3
// baseline (3653.436 us; speedup 1.0000x reference)
//
#include <hip/hip_runtime.h>
#include <math.h>

#define N_NODES    100000
#define K_NEIGH    32
#define OUT_STRIDE 448      // 3*128 + 64
#define NPASS      4
#define PRANGE     25000    // nodes per pass slab: 25000 * 128B = 3.2 MB < 4 MB L2
#define ACC_GRID   1000     // co-resident (4 blocks/CU * 256 CUs = 1024 >= 1000)
#define NW         25       // nodes per wave: 1000 blocks * 4 waves * 25 = 100000 exactly
#define PREP_NPB   128      // prep nodes per block

typedef __attribute__((ext_vector_type(8))) __bf16 bf16x8;
typedef __attribute__((ext_vector_type(4))) float  f32x4;

// bf16 helpers (RNE)
static __device__ __forceinline__ unsigned short f2bf(float f) {
    unsigned int u = __float_as_uint(f);
    return (unsigned short)((u + 0x7FFFu + ((u >> 16) & 1u)) >> 16);
}
static __device__ __forceinline__ float bf2f(unsigned short h) {
    return __uint_as_float(((unsigned int)h) << 16);
}

// ---------------------------------------------------------------------------
// Prep: per-node bucket sort of edges by pass = j/25000 (sum/max are
// permutation-invariant, so reordering each node's neighbor list is legal).
//   iwb[n][0..31]  = (j<<15)|w15 edges, grouped by pass
//   cnts[n]        = 4x8-bit per-pass counts
// idx/dist staged via coalesced loads into LDS, then 1 thread per node sorts.
// Branch-free bucket fill via packed 8-bit counters (no scratch arrays).
// Also: bf16 transposed weights for dense, and barrier-counter reset.
// ---------------------------------------------------------------------------
__global__ __launch_bounds__(256) void prep_kernel(
    const float* __restrict__ dist, const int* __restrict__ idx,
    unsigned int* __restrict__ iwb, unsigned int* __restrict__ cnts,
    const float* __restrict__ W0, const float* __restrict__ W1,
    const float* __restrict__ W2,
    unsigned short* __restrict__ Wt0, unsigned short* __restrict__ Wt1,
    unsigned short* __restrict__ Wt2, unsigned int* __restrict__ bar)
{
    __shared__ int   idxLDS[PREP_NPB * K_NEIGH];
    __shared__ float dstLDS[PREP_NPB * K_NEIGH];

    const int tid = threadIdx.x;
    const int gi  = blockIdx.x * 256 + tid;

    if (gi == 0) bar[0] = 0u;
    if (gi < 64 * 64)  Wt0[(gi & 63) * 64  + (gi >> 6)] = f2bf(W0[gi]);  // gi = k*64+n
    if (gi < 128 * 64) Wt1[(gi & 63) * 128 + (gi >> 6)] = f2bf(W1[gi]);
    if (gi < 128 * 64) Wt2[(gi & 63) * 128 + (gi >> 6)] = f2bf(W2[gi]);

    const int nb0 = blockIdx.x * PREP_NPB;
    for (int t = tid; t < PREP_NPB * K_NEIGH; t += 256) {
        if (nb0 + (t >> 5) < N_NODES) {
            const size_t g = (size_t)nb0 * K_NEIGH + t;
            idxLDS[t] = idx[g];
            dstLDS[t] = dist[g];
        }
    }
    __syncthreads();

    if (tid < PREP_NPB) {
        const int n = nb0 + tid;
        if (n < N_NODES) {
            const int base = tid * K_NEIGH;
            unsigned int pk = 0;   // packed per-pass counts
            for (int k = 0; k < K_NEIGH; ++k) {
                const unsigned j = (unsigned)idxLDS[base + k];
                pk += 1u << (8 * (j / PRANGE));
            }
            cnts[n] = pk;
            const unsigned c0 = pk & 255u, c1 = (pk >> 8) & 255u, c2 = (pk >> 16) & 255u;
            const unsigned s1 = c0, s2 = c0 + c1, s3 = s2 + c2;
            unsigned int fill = 0;  // packed per-pass fill cursors
            for (int k = 0; k < K_NEIGH; ++k) {
                const unsigned j = (unsigned)idxLDS[base + k];
                const unsigned p = j / PRANGE;
                const float w = __expf(-10.f * dstLDS[base + k]);
                const unsigned w15 = (unsigned)(w * 32767.f + 0.5f);
                const unsigned pos = (fill >> (8 * p)) & 255u;
                fill += 1u << (8 * p);
                const unsigned st = (p == 0) ? 0u : (p == 1) ? s1 : (p == 2) ? s2 : s3;
                iwb[(size_t)n * K_NEIGH + st + pos] = (j << 15) | w15;
            }
        }
    }
}

// ---------------------------------------------------------------------------
// Dense layer via MFMA (unchanged structure; F back to row-major [n][64]).
// ---------------------------------------------------------------------------
template <int DIN, bool COPY_X>
__global__ __launch_bounds__(256) void dense_kernel(
    const float* __restrict__ in, int in_stride,
    const unsigned short* __restrict__ Wt,   // [64][DIN] bf16 (transposed W)
    const float* __restrict__ b,
    unsigned short* __restrict__ F, float* __restrict__ out)
{
    constexpr int LDK = DIN + 8;
    __shared__ unsigned short aLDS[64 * LDK];
    __shared__ unsigned short bLDS[64 * LDK];

    const int tid  = threadIdx.x;
    const int row0 = blockIdx.x * 64;

    for (int i = tid; i < 64 * (DIN / 4); i += 256) {
        const int r = i / (DIN / 4);
        const int c = (i % (DIN / 4)) * 4;
        const int n = row0 + r;
        float4 v = make_float4(0.f, 0.f, 0.f, 0.f);
        if (n < N_NODES) {
            v = *(const float4*)&in[(size_t)n * in_stride + c];
            if (COPY_X) *(float4*)&out[(size_t)n * OUT_STRIDE + 384 + c] = v;
        }
        const unsigned int u0 = (unsigned int)f2bf(v.x) | ((unsigned int)f2bf(v.y) << 16);
        const unsigned int u1 = (unsigned int)f2bf(v.z) | ((unsigned int)f2bf(v.w) << 16);
        *(uint2*)&aLDS[r * LDK + c] = make_uint2(u0, u1);
    }
    for (int i = tid; i < 64 * (DIN / 8); i += 256) {
        const int nn = i / (DIN / 8);
        const int k0 = (i % (DIN / 8)) * 8;
        *(uint4*)&bLDS[nn * LDK + k0] = *(const uint4*)&Wt[nn * DIN + k0];
    }
    __syncthreads();

    const int lane = tid & 63;
    const int wv   = tid >> 6;
    const int m    = lane & 15;
    const int quad = lane >> 4;

    f32x4 acc[4];
#pragma unroll
    for (int nb = 0; nb < 4; ++nb) acc[nb] = (f32x4){0.f, 0.f, 0.f, 0.f};

#pragma unroll
    for (int ks = 0; ks < DIN / 32; ++ks) {
        const int koff = ks * 32 + quad * 8;
        const bf16x8 afr =
            *reinterpret_cast<const bf16x8*>(&aLDS[(wv * 16 + m) * LDK + koff]);
#pragma unroll
        for (int nb = 0; nb < 4; ++nb) {
            const bf16x8 bfr =
                *reinterpret_cast<const bf16x8*>(&bLDS[(nb * 16 + m) * LDK + koff]);
            acc[nb] = __builtin_amdgcn_mfma_f32_16x16x32_bf16(afr, bfr, acc[nb], 0, 0, 0);
        }
    }

#pragma unroll
    for (int nb = 0; nb < 4; ++nb) {
        const int c    = nb * 16 + m;
        const float bc = b[c];
#pragma unroll
        for (int reg = 0; reg < 4; ++reg) {
            const int n = row0 + wv * 16 + quad * 4 + reg;
            if (n < N_NODES) {
                const float vv = fmaxf(acc[nb][reg] + bc, 0.f);
                F[(size_t)n * 64 + c] = f2bf(vv);
            }
        }
    }
}

// ---------------------------------------------------------------------------
// KNN accumulate v4: pass-phased L2-resident gather.
//   Pass p gathers only edges with j in [p*25000,(p+1)*25000): a contiguous
//   3.2 MB slab of FULL 128B rows -> fits every XCD's 4 MB L2; all XCDs work
//   the same slab simultaneously, paced by a grid-wide ticket barrier.
//   Wave-uniform node => edge words via scalar loads (SMEM pipe); gather is
//   1 ushort/lane = one fully-used 128B line per edge (v1's optimal shape).
//   sum/max accumulators live in registers across passes (static indexing).
//   Barrier: co-resident by construction (1000 blocks, 4 blocks/CU bound);
//   bounded spin so a capacity miscalculation degrades instead of hanging.
// ---------------------------------------------------------------------------
__global__ __launch_bounds__(256, 4) void acc_kernel(
    const unsigned short* __restrict__ F,
    const unsigned int* __restrict__ iwb,
    const unsigned int* __restrict__ cnts,
    float* __restrict__ out,          // already offset to this layer's slab
    unsigned int* __restrict__ bar)
{
    const int tid  = threadIdx.x;
    const int lane = tid & 63;
    const int wid  = __builtin_amdgcn_readfirstlane(blockIdx.x * 4 + (tid >> 6));
    const int n0   = wid * NW;

    float sum[NW], mx[NW];
#pragma unroll
    for (int i = 0; i < NW; ++i) { sum[i] = 0.f; mx[i] = -INFINITY; }

    for (int p = 0; p < NPASS; ++p) {
#pragma unroll
        for (int i = 0; i < NW; ++i) {
            const int n = n0 + i;
            const unsigned pk = cnts[n];                        // uniform -> SGPR
            const unsigned c0 = pk & 255u, c1 = (pk >> 8) & 255u, c2 = (pk >> 16) & 255u;
            const unsigned cnt = (pk >> (8 * p)) & 255u;
            const unsigned st  = (p == 0) ? 0u : (p == 1) ? c0
                               : (p == 2) ? (c0 + c1) : (c0 + c1 + c2);
            const unsigned* __restrict__ ep = iwb + (size_t)n * K_NEIGH + st;
            for (unsigned t = 0; t < cnt; ++t) {
                const unsigned e  = ep[t];                      // uniform -> SGPR
                const float    wk = (float)(e & 0x7FFFu) * (1.f / 32767.f);
                const float    g  = bf2f(F[(size_t)(e >> 15) * 64 + lane]);
                const float    v  = wk * g;
                sum[i] += v;
                mx[i]  = fmaxf(mx[i], v);
            }
        }
        if (p < NPASS - 1) {
            __syncthreads();
            if (tid == 0) {
                const unsigned tk = __hip_atomic_fetch_add(
                    bar, 1u, __ATOMIC_ACQ_REL, __HIP_MEMORY_SCOPE_AGENT);
                const unsigned target = (tk / ACC_GRID + 1u) * ACC_GRID;
                int spins = 0;
                while (__hip_atomic_load(bar, __ATOMIC_ACQUIRE,
                                         __HIP_MEMORY_SCOPE_AGENT) < target) {
                    __builtin_amdgcn_s_sleep(2);
                    if (++spins > 200000) break;   // failsafe: degrade, never hang
                }
            }
            __syncthreads();
        }
    }

    // Epilogue: prev rows are sequential per wave -> streaming reads.
#pragma unroll
    for (int i = 0; i < NW; ++i) {
        const int n = n0 + i;
        const float prev = bf2f(F[(size_t)n * 64 + lane]);
        float* orow = out + (size_t)n * OUT_STRIDE + lane;
        __builtin_nontemporal_store(sum[i] * (1.f / 32.f) - prev, orow);
        __builtin_nontemporal_store(mx[i] - prev, orow + 64);
    }
}

// ---------------------------------------------------------------------------
extern "C" void kernel_launch(void* const* d_in, const int* in_sizes, int n_in,
                              void* d_out, int out_size, void* d_ws, size_t ws_size,
                              hipStream_t stream)
{
    const float* x    = (const float*)d_in[0];
    const int*   idx  = (const int*)  d_in[1];
    const float* dist = (const float*)d_in[2];
    const float* W0   = (const float*)d_in[3];
    const float* b0   = (const float*)d_in[4];
    const float* W1   = (const float*)d_in[5];
    const float* b1   = (const float*)d_in[6];
    const float* W2   = (const float*)d_in[7];
    const float* b2   = (const float*)d_in[8];

    float* out = (float*)d_out;

    // Workspace layout (all 16B-aligned):
    char* ws = (char*)d_ws;
    unsigned short* F    = (unsigned short*)(ws);                 // 12.8 MB
    unsigned int*   iwb  = (unsigned int*)  (ws + 12800000);      // 12.8 MB
    unsigned int*   cnts = (unsigned int*)  (ws + 25600000);      // 400 KB
    unsigned short* Wt0  = (unsigned short*)(ws + 26000000);      // 8 KB
    unsigned short* Wt1  = (unsigned short*)(ws + 26008192);      // 16 KB
    unsigned short* Wt2  = (unsigned short*)(ws + 26024576);      // 16 KB
    unsigned int*   bar  = (unsigned int*)  (ws + 26040960);      // 4 B

    const int prep_grid  = (N_NODES + PREP_NPB - 1) / PREP_NPB;  // 782
    const int dense_grid = (N_NODES + 63) / 64;                  // 1563

    prep_kernel<<<prep_grid, 256, 0, stream>>>(dist, idx, iwb, cnts,
                                               W0, W1, W2, Wt0, Wt1, Wt2, bar);

    // Layer 0: dense from x (also copies x into out[:,384:448])
    dense_kernel<64, true><<<dense_grid, 256, 0, stream>>>(x, 64, Wt0, b0, F, out);
    acc_kernel<<<ACC_GRID, 256, 0, stream>>>(F, iwb, cnts, out + 0, bar);

    // Layer 1: dense reads layer-0 slab of out (it IS the next input)
    dense_kernel<128, false><<<dense_grid, 256, 0, stream>>>(out + 0, OUT_STRIDE, Wt1, b1, F, nullptr);
    acc_kernel<<<ACC_GRID, 256, 0, stream>>>(F, iwb, cnts, out + 128, bar);

    // Layer 2
    dense_kernel<128, false><<<dense_grid, 256, 0, stream>>>(out + 128, OUT_STRIDE, Wt2, b2, F, nullptr);
    acc_kernel<<<ACC_GRID, 256, 0, stream>>>(F, iwb, cnts, out + 256, bar);
}

// Round 4
// 1757.875 us; speedup vs baseline: 2.0783x; 2.0783x over previous
//
#include <hip/hip_runtime.h>
#include <math.h>

#define N_NODES    100000
#define K_NEIGH    32
#define OUT_STRIDE 448      // 3*128 + 64
#define NPASS      4
#define PRANGE     25000    // slab: 25000 rows * 128B = 3.2 MB < 4 MB per-XCD L2
#define ACC_GRID   1000     // co-resident: 4 blocks/CU * 256 CU = 1024 >= 1000
#define NW         25       // nodes per wave: 1000*4*25 = 100000 exactly
#define PREP_NPB   128      // prep nodes per block

typedef __attribute__((ext_vector_type(8))) __bf16 bf16x8;
typedef __attribute__((ext_vector_type(4))) float  f32x4;

// bf16 helpers (RNE)
static __device__ __forceinline__ unsigned short f2bf(float f) {
    unsigned int u = __float_as_uint(f);
    return (unsigned short)((u + 0x7FFFu + ((u >> 16) & 1u)) >> 16);
}
static __device__ __forceinline__ float bf2f(unsigned short h) {
    return __uint_as_float(((unsigned int)h) << 16);
}

// ---------------------------------------------------------------------------
// Prep: per-node FULL SORT of edges by neighbor index j (sum/max are
// permutation-invariant -> legal). Packed e = (j<<15) | w15; j is the high
// bits so sorting e ascending sorts by j. acc then processes positions
// [8p, 8p+8) during pass p: ~81% of gathers hit the pass-p slab with a
// perfectly STATIC schedule (no counts, no predicates, no scalar chains).
// Also: bf16 transposed weights for dense; barrier counter reset.
// ---------------------------------------------------------------------------
__global__ __launch_bounds__(256) void prep_kernel(
    const float* __restrict__ dist, const int* __restrict__ idx,
    unsigned int* __restrict__ iwb,
    const float* __restrict__ W0, const float* __restrict__ W1,
    const float* __restrict__ W2,
    unsigned short* __restrict__ Wt0, unsigned short* __restrict__ Wt1,
    unsigned short* __restrict__ Wt2, unsigned int* __restrict__ bar)
{
    __shared__ unsigned int eLDS[PREP_NPB * 33];   // padded: bank-spread slices
    __shared__ float        dLDS[PREP_NPB * K_NEIGH];

    const int tid = threadIdx.x;
    const int gi  = blockIdx.x * 256 + tid;

    if (gi == 0) bar[0] = 0u;
    if (gi < 64 * 64)  Wt0[(gi & 63) * 64  + (gi >> 6)] = f2bf(W0[gi]);  // gi = k*64+n
    if (gi < 128 * 64) Wt1[(gi & 63) * 128 + (gi >> 6)] = f2bf(W1[gi]);
    if (gi < 128 * 64) Wt2[(gi & 63) * 128 + (gi >> 6)] = f2bf(W2[gi]);

    const int nb0 = blockIdx.x * PREP_NPB;
    for (int t = tid; t < PREP_NPB * K_NEIGH; t += 256) {
        if (nb0 + (t >> 5) < N_NODES) {
            const size_t g = (size_t)nb0 * K_NEIGH + t;
            eLDS[(t >> 5) * 33 + (t & 31)] = (unsigned int)idx[g];
            dLDS[t] = dist[g];
        }
    }
    __syncthreads();

    if (tid < PREP_NPB && nb0 + tid < N_NODES) {
        const int base = tid * 33;
        // pack keys: (j<<15)|w15
        for (int k = 0; k < K_NEIGH; ++k) {
            const unsigned j = eLDS[base + k];
            const float w = __expf(-10.f * dLDS[tid * K_NEIGH + k]);
            const unsigned w15 = (unsigned)(w * 32767.f + 0.5f);
            eLDS[base + k] = (j << 15) | w15;
        }
        // insertion sort ascending (== sort by j)
        for (int k = 1; k < K_NEIGH; ++k) {
            const unsigned key = eLDS[base + k];
            int m = k - 1;
            while (m >= 0 && eLDS[base + m] > key) {
                eLDS[base + m + 1] = eLDS[base + m];
                --m;
            }
            eLDS[base + m + 1] = key;
        }
    }
    __syncthreads();

    for (int t = tid; t < PREP_NPB * K_NEIGH; t += 256) {
        if (nb0 + (t >> 5) < N_NODES)
            iwb[(size_t)nb0 * K_NEIGH + t] = eLDS[(t >> 5) * 33 + (t & 31)];
    }
}

// ---------------------------------------------------------------------------
// Dense layer via MFMA (unchanged; F row-major [n][64] bf16).
// ---------------------------------------------------------------------------
template <int DIN, bool COPY_X>
__global__ __launch_bounds__(256) void dense_kernel(
    const float* __restrict__ in, int in_stride,
    const unsigned short* __restrict__ Wt,   // [64][DIN] bf16 (transposed W)
    const float* __restrict__ b,
    unsigned short* __restrict__ F, float* __restrict__ out)
{
    constexpr int LDK = DIN + 8;
    __shared__ unsigned short aLDS[64 * LDK];
    __shared__ unsigned short bLDS[64 * LDK];

    const int tid  = threadIdx.x;
    const int row0 = blockIdx.x * 64;

    for (int i = tid; i < 64 * (DIN / 4); i += 256) {
        const int r = i / (DIN / 4);
        const int c = (i % (DIN / 4)) * 4;
        const int n = row0 + r;
        float4 v = make_float4(0.f, 0.f, 0.f, 0.f);
        if (n < N_NODES) {
            v = *(const float4*)&in[(size_t)n * in_stride + c];
            if (COPY_X) *(float4*)&out[(size_t)n * OUT_STRIDE + 384 + c] = v;
        }
        const unsigned int u0 = (unsigned int)f2bf(v.x) | ((unsigned int)f2bf(v.y) << 16);
        const unsigned int u1 = (unsigned int)f2bf(v.z) | ((unsigned int)f2bf(v.w) << 16);
        *(uint2*)&aLDS[r * LDK + c] = make_uint2(u0, u1);
    }
    for (int i = tid; i < 64 * (DIN / 8); i += 256) {
        const int nn = i / (DIN / 8);
        const int k0 = (i % (DIN / 8)) * 8;
        *(uint4*)&bLDS[nn * LDK + k0] = *(const uint4*)&Wt[nn * DIN + k0];
    }
    __syncthreads();

    const int lane = tid & 63;
    const int wv   = tid >> 6;
    const int m    = lane & 15;
    const int quad = lane >> 4;

    f32x4 acc[4];
#pragma unroll
    for (int nb = 0; nb < 4; ++nb) acc[nb] = (f32x4){0.f, 0.f, 0.f, 0.f};

#pragma unroll
    for (int ks = 0; ks < DIN / 32; ++ks) {
        const int koff = ks * 32 + quad * 8;
        const bf16x8 afr =
            *reinterpret_cast<const bf16x8*>(&aLDS[(wv * 16 + m) * LDK + koff]);
#pragma unroll
        for (int nb = 0; nb < 4; ++nb) {
            const bf16x8 bfr =
                *reinterpret_cast<const bf16x8*>(&bLDS[(nb * 16 + m) * LDK + koff]);
            acc[nb] = __builtin_amdgcn_mfma_f32_16x16x32_bf16(afr, bfr, acc[nb], 0, 0, 0);
        }
    }

#pragma unroll
    for (int nb = 0; nb < 4; ++nb) {
        const int c    = nb * 16 + m;
        const float bc = b[c];
#pragma unroll
        for (int reg = 0; reg < 4; ++reg) {
            const int n = row0 + wv * 16 + quad * 4 + reg;
            if (n < N_NODES) {
                const float vv = fmaxf(acc[nb][reg] + bc, 0.f);
                F[(size_t)n * 64 + c] = f2bf(vv);
            }
        }
    }
}

// ---------------------------------------------------------------------------
// KNN accumulate v5: pass-phased + STATIC schedule.
//   Edges pre-sorted by j; pass p processes positions [8p,8p+8) of every
//   node -> ~81% of gathers target the resident 3.2 MB slab. Fixed trip
//   counts everywhere: per (p,t) the unrolled 25-slot loop issues 25
//   INDEPENDENT gathers (edge words from LDS broadcast reads with immediate
//   offsets) -> deep MLP restored, no scalar-load chains, no waitcnt(0)
//   serialization. Register accumulators, statically indexed.
//   Barrier: 1000 blocks co-resident (4 blocks/CU via launch_bounds);
//   s_sleep(32) poll (853ns) so 1000 spinners don't saturate the counter
//   line's L2; bounded spins = degrade-not-hang failsafe.
// ---------------------------------------------------------------------------
__global__ __launch_bounds__(256, 4) void acc_kernel(
    const unsigned short* __restrict__ F,
    const unsigned int* __restrict__ iwb,   // [N][32] sorted (j<<15)|w15
    float* __restrict__ out,                // already offset to layer slab
    unsigned int* __restrict__ bar)
{
    __shared__ unsigned int eLDS[4 * NW * K_NEIGH];   // 3200 words = 12.8 KB

    const int tid  = threadIdx.x;
    const int lane = tid & 63;
    const int wv   = tid >> 6;

    // Stage this block's 100 nodes x 32 edge words (coalesced)
    const unsigned int* __restrict__ gsrc = iwb + (size_t)blockIdx.x * (4 * NW * K_NEIGH);
    for (int t = tid; t < 4 * NW * K_NEIGH; t += 256) eLDS[t] = gsrc[t];
    __syncthreads();

    const int n0    = (blockIdx.x * 4 + wv) * NW;
    const int lane2 = lane * 2;
    const char* __restrict__ Fb = (const char*)F;

    float sum[NW], mx[NW];
#pragma unroll
    for (int i = 0; i < NW; ++i) { sum[i] = 0.f; mx[i] = -INFINITY; }

    for (int p = 0; p < NPASS; ++p) {
        for (int t = 0; t < 8; ++t) {
            const int koff = wv * NW * K_NEIGH + p * 8 + t;
#pragma unroll
            for (int i = 0; i < NW; ++i) {
                const unsigned e  = eLDS[koff + i * K_NEIGH];   // broadcast ds_read, imm offset
                const float    wk = (float)(e & 0x7FFFu) * (1.f / 32767.f);
                const unsigned vo = (e >> 15) * 128u + (unsigned)lane2;
                const float    g  = bf2f(*(const unsigned short*)(Fb + vo));
                const float    v  = wk * g;
                sum[i] += v;
                mx[i]  = fmaxf(mx[i], v);
            }
        }
        if (p < NPASS - 1) {
            __syncthreads();
            if (tid == 0) {
                const unsigned tk = __hip_atomic_fetch_add(
                    bar, 1u, __ATOMIC_ACQ_REL, __HIP_MEMORY_SCOPE_AGENT);
                const unsigned target = (tk / ACC_GRID + 1u) * ACC_GRID;
                int spins = 0;
                while (__hip_atomic_load(bar, __ATOMIC_ACQUIRE,
                                         __HIP_MEMORY_SCOPE_AGENT) < target) {
                    __builtin_amdgcn_s_sleep(32);     // ~853ns poll: low contention
                    if (++spins > 8000) break;        // failsafe: degrade, never hang
                }
            }
            __syncthreads();
        }
    }

    // Epilogue: prev rows sequential per wave -> coalesced streaming reads.
#pragma unroll
    for (int i = 0; i < NW; ++i) {
        const int n = n0 + i;
        const float prev = bf2f(F[(size_t)n * 64 + lane]);
        float* orow = out + (size_t)n * OUT_STRIDE + lane;
        __builtin_nontemporal_store(sum[i] * (1.f / 32.f) - prev, orow);
        __builtin_nontemporal_store(mx[i] - prev, orow + 64);
    }
}

// ---------------------------------------------------------------------------
extern "C" void kernel_launch(void* const* d_in, const int* in_sizes, int n_in,
                              void* d_out, int out_size, void* d_ws, size_t ws_size,
                              hipStream_t stream)
{
    const float* x    = (const float*)d_in[0];
    const int*   idx  = (const int*)  d_in[1];
    const float* dist = (const float*)d_in[2];
    const float* W0   = (const float*)d_in[3];
    const float* b0   = (const float*)d_in[4];
    const float* W1   = (const float*)d_in[5];
    const float* b1   = (const float*)d_in[6];
    const float* W2   = (const float*)d_in[7];
    const float* b2   = (const float*)d_in[8];

    float* out = (float*)d_out;

    // Workspace layout (all 16B-aligned):
    char* ws = (char*)d_ws;
    unsigned short* F    = (unsigned short*)(ws);                 // 12.8 MB
    unsigned int*   iwb  = (unsigned int*)  (ws + 12800000);      // 12.8 MB
    unsigned short* Wt0  = (unsigned short*)(ws + 25600000);      // 8 KB
    unsigned short* Wt1  = (unsigned short*)(ws + 25608192);      // 16 KB
    unsigned short* Wt2  = (unsigned short*)(ws + 25624576);      // 16 KB
    unsigned int*   bar  = (unsigned int*)  (ws + 25640960);      // 4 B

    const int prep_grid  = (N_NODES + PREP_NPB - 1) / PREP_NPB;  // 782
    const int dense_grid = (N_NODES + 63) / 64;                  // 1563

    prep_kernel<<<prep_grid, 256, 0, stream>>>(dist, idx, iwb,
                                               W0, W1, W2, Wt0, Wt1, Wt2, bar);

    // Layer 0: dense from x (also copies x into out[:,384:448])
    dense_kernel<64, true><<<dense_grid, 256, 0, stream>>>(x, 64, Wt0, b0, F, out);
    acc_kernel<<<ACC_GRID, 256, 0, stream>>>(F, iwb, out + 0, bar);

    // Layer 1: dense reads layer-0 slab of out (it IS the next input)
    dense_kernel<128, false><<<dense_grid, 256, 0, stream>>>(out + 0, OUT_STRIDE, Wt1, b1, F, nullptr);
    acc_kernel<<<ACC_GRID, 256, 0, stream>>>(F, iwb, out + 128, bar);

    // Layer 2
    dense_kernel<128, false><<<dense_grid, 256, 0, stream>>>(out + 128, OUT_STRIDE, Wt2, b2, F, nullptr);
    acc_kernel<<<ACC_GRID, 256, 0, stream>>>(F, iwb, out + 256, bar);
}